// Round 11
// baseline (169.653 us; speedup 1.0000x reference)
//
#include <hip/hip_runtime.h>
#include <stdint.h>

#define NB 32
#define NN 25200
#define NN4 6300          // NN/4, exact
#define TOPK 1024
#define NF 16
#define CONF 0.25f
#define IOU_T 0.45f
#define NBIN 4096
#define CAP 2048
#define KEY_BASE 0xBE800001u  // lowest possible valid key (score just above 0.25)

// monotone-ascending uint32 map of the reference's s = valid ? obj*cls : -1.0
__device__ __forceinline__ uint32_t score_key(float obj, float cls) {
  float score = __fmul_rn(cls, obj);
  bool valid = (obj > CONF) && (score > CONF);
  float s = valid ? score : -1.0f;
  uint32_t u = __float_as_uint(s);
  return (u & 0x80000000u) ? ~u : (u | 0x80000000u);
}

__device__ __forceinline__ uint64_t shfl_xor_u64(uint64_t v, int m) {
  uint32_t lo = __shfl_xor((uint32_t)v, m, 64);
  uint32_t hi = __shfl_xor((uint32_t)(v >> 32), m, 64);
  return ((uint64_t)hi << 32) | lo;
}

// Full-grid key compute: the 51.6 MB strided pred read spread over all 256 CUs
// (R8 lesson: folding this into the 32-block select kernel is a 5x loss).
__global__ void k_keys(const float* __restrict__ pred, uint32_t* __restrict__ keys) {
  int g = blockIdx.x * blockDim.x + threadIdx.x;
  if (g >= NB * NN) return;
  const float* row = pred + (size_t)g * NF;
  keys[g] = score_key(row[4], row[15]);
}

// One block per image. Keys read ONCE into registers (<=7 uint4/thread);
// uniform 4096-bin histogram over the valid-key range -> suffix-scan for the
// rank-1024 crossing bin -> compact bins >= b* (~1026 els, CAP=2048
// zero-padded) -> register bitonic 2048 descending on (key32<<32 | ~n).
// Exact jax.lax.top_k order. Also zeroes cnt[b] for k_mask_scan (kernel
// boundary ordering makes it visible).
__global__ __launch_bounds__(1024) void k_select(const uint32_t* __restrict__ keys,
                                                 int* __restrict__ sel,
                                                 uint32_t* __restrict__ cnt) {
  int b = blockIdx.x;
  int tid = threadIdx.x;
  int lane = tid & 63, wid = tid >> 6;
  const uint4* kb4 = (const uint4*)(keys + (size_t)b * NN);
  __shared__ uint32_t hist[NBIN];
  __shared__ uint64_t ent[CAP];
  __shared__ uint32_t wsum[16];
  __shared__ uint32_t sh_bin;
  __shared__ uint32_t sh_cnt;
  #pragma unroll
  for (int k = 0; k < 4; ++k) hist[tid + 1024 * k] = 0;
  ent[tid] = 0; ent[tid + 1024] = 0;
  if (tid == 0) { sh_cnt = 0; sh_bin = 0; cnt[b] = 0; }
  __syncthreads();

  // phase 1: load keys into registers (single global pass) + histogram
  uint4 kreg[7];
  #pragma unroll
  for (int k = 0; k < 7; ++k) {
    int i = tid + k * 1024;
    if (i < NN4) {
      kreg[k] = kb4[i];
      uint32_t kv[4] = {kreg[k].x, kreg[k].y, kreg[k].z, kreg[k].w};
      #pragma unroll
      for (int c = 0; c < 4; ++c) {
        uint32_t key = kv[c];
        if (key >= KEY_BASE) {
          uint32_t bin = (key - KEY_BASE) >> 12;
          if (bin > NBIN - 1) bin = NBIN - 1;
          atomicAdd(&hist[bin], 1u);
        }
      }
    }
  }
  __syncthreads();

  // phase 2: descending-bin cumulative via shfl scan; find crossing bin
  uint32_t h[4]; uint32_t s = 0;
  #pragma unroll
  for (int k = 0; k < 4; ++k) { h[k] = hist[NBIN - 1 - (4 * tid + k)]; s += h[k]; }
  uint32_t my = s;
  #pragma unroll
  for (int d = 1; d < 64; d <<= 1) {
    uint32_t v = __shfl_up(s, d, 64);
    if (lane >= d) s += v;
  }
  if (lane == 63) wsum[wid] = s;
  __syncthreads();
  uint32_t base = 0;
  for (int w = 0; w < wid; ++w) base += wsum[w];
  uint32_t cum = base + s - my;  // exclusive prefix (descending bins)
  #pragma unroll
  for (int k = 0; k < 4; ++k) {
    if (cum < TOPK && cum + h[k] >= TOPK) sh_bin = (uint32_t)(NBIN - 1 - (4 * tid + k));
    cum += h[k];
  }
  __syncthreads();
  uint32_t thr = KEY_BASE + (sh_bin << 12);

  // phase 3: compact from registers (no second global pass)
  #pragma unroll
  for (int k = 0; k < 7; ++k) {
    int i = tid + k * 1024;
    if (i < NN4) {
      uint32_t kv[4] = {kreg[k].x, kreg[k].y, kreg[k].z, kreg[k].w};
      #pragma unroll
      for (int c = 0; c < 4; ++c) {
        uint32_t key = kv[c];
        if (key >= thr) {
          uint32_t p = atomicAdd(&sh_cnt, 1u);
          if (p < CAP) ent[p] = ((uint64_t)key << 32) | (uint32_t)(~(uint32_t)(4 * i + c));
        }
      }
    }
  }
  __syncthreads();

  // phase 4: register bitonic, 2048 descending, 2 elems/thread
  uint64_t v0 = ent[tid], v1 = ent[tid + 1024];
  for (unsigned kk = 2; kk <= CAP; kk <<= 1) {
    for (unsigned j = kk >> 1; j > 0; j >>= 1) {
      if (j == 1024) {
        uint64_t mx = v0 > v1 ? v0 : v1;
        uint64_t mn = v0 > v1 ? v1 : v0;
        v0 = mx; v1 = mn;  // desc=true for kk=2048
      } else if (j >= 64) {
        __syncthreads();
        ent[tid] = v0; ent[tid + 1024] = v1;
        __syncthreads();
        uint64_t p0 = ent[tid ^ j], p1 = ent[(tid ^ j) + 1024];
        bool low = ((tid & j) == 0);
        bool d0 = ((tid & kk) == 0);
        bool d1 = (((tid + 1024) & kk) == 0);
        v0 = (low != d0) ? (v0 < p0 ? v0 : p0) : (v0 > p0 ? v0 : p0);
        v1 = (low != d1) ? (v1 < p1 ? v1 : p1) : (v1 > p1 ? v1 : p1);
      } else {
        uint64_t p0 = shfl_xor_u64(v0, (int)j);
        uint64_t p1 = shfl_xor_u64(v1, (int)j);
        bool low = ((tid & j) == 0);
        bool d0 = ((tid & kk) == 0);
        bool d1 = (((tid + 1024) & kk) == 0);
        v0 = (low != d0) ? (v0 < p0 ? v0 : p0) : (v0 > p0 ? v0 : p0);
        v1 = (low != d1) ? (v1 < p1 ? v1 : p1) : (v1 > p1 ? v1 : p1);
      }
    }
  }
  uint32_t n = ~(uint32_t)(v0 & 0xFFFFFFFFu);
  if (n >= NN) n = 0;  // safety only
  sel[(size_t)b * TOPK + tid] = (int)n;
}

// grid (NB, 8): mask compute (thread = 4-row x 32-col tile, column-major
// mask[b][word][row], uint4 stores). After its stores each block
// release-fences and bumps cnt[b] (agent scope); the 8th block acquire-fences
// and runs the word-serial greedy scan + masked output for the whole image.
// Scan latency hides under other images' mask compute; one less launch gap.
__global__ __launch_bounds__(1024) void k_mask_scan(const float* __restrict__ pred,
                                                    const int* __restrict__ sel,
                                                    uint32_t* __restrict__ mask,
                                                    uint32_t* __restrict__ cnt,
                                                    float* __restrict__ det,
                                                    float* __restrict__ keep_out) {
  int b = blockIdx.x;
  int sblk = blockIdx.y;
  int tid = threadIdx.x;
  int rg = tid & 31;
  int cc = tid >> 5;
  __shared__ float bx1[TOPK], by1[TOPK], bx2[TOPK], by2[TOPK], bar[TOPK];
  __shared__ uint32_t sh_old;
  __shared__ uint32_t vbits[32];
  __shared__ uint32_t keepw[32];

  int n = sel[(size_t)b * TOPK + tid];
  {
    const float4* row = (const float4*)(pred + ((size_t)b * NN + n) * NF);
    float4 r0 = row[0];
    float hw = __fmul_rn(r0.z, 0.5f), hh = __fmul_rn(r0.w, 0.5f);
    float x1 = __fsub_rn(r0.x, hw), y1 = __fsub_rn(r0.y, hh);
    float x2 = __fadd_rn(r0.x, hw), y2 = __fadd_rn(r0.y, hh);
    bx1[tid] = x1; by1[tid] = y1; bx2[tid] = x2; by2[tid] = y2;
    bar[tid] = __fmul_rn(__fsub_rn(x2, x1), __fsub_rn(y2, y1));
  }
  __syncthreads();

  // ---- mask tile compute
  int i0 = sblk * 128 + rg * 4;   // rows i0..i0+3, all in word iw
  int iw = i0 >> 5;
  uint32_t wreg[4] = {0u, 0u, 0u, 0u};
  if (cc >= iw) {
    float rx1[4], ry1[4], rx2[4], ry2[4], rar[4];
    #pragma unroll
    for (int k = 0; k < 4; ++k) {
      rx1[k] = bx1[i0 + k]; ry1[k] = by1[i0 + k];
      rx2[k] = bx2[i0 + k]; ry2[k] = by2[i0 + k]; rar[k] = bar[i0 + k];
    }
    for (int jj = 0; jj < 32; ++jj) {
      int j = cc * 32 + jj;
      float cx1 = bx1[j], cy1 = by1[j], cx2 = bx2[j], cy2 = by2[j], car = bar[j];
      #pragma unroll
      for (int k = 0; k < 4; ++k) {
        float lx = fmaxf(rx1[k], cx1);
        float ly = fmaxf(ry1[k], cy1);
        float rx = fminf(rx2[k], cx2);
        float ry = fminf(ry2[k], cy2);
        float wd = fmaxf(__fsub_rn(rx, lx), 0.0f);
        float ht = fmaxf(__fsub_rn(ry, ly), 0.0f);
        float inter = __fmul_rn(wd, ht);
        float den = __fadd_rn(__fsub_rn(__fadd_rn(rar[k], car), inter), 1e-7f);
        float iou = __fdiv_rn(inter, den);
        wreg[k] |= (iou > IOU_T ? 1u : 0u) << jj;
      }
    }
    if (cc == iw) {
      #pragma unroll
      for (int k = 0; k < 4; ++k)
        wreg[k] &= ~((2u << ((i0 + k) & 31)) - 1u);  // keep only j > i
    }
  }
  *(uint4*)&mask[((size_t)b * 32 + cc) * TOPK + i0] =
      make_uint4(wreg[0], wreg[1], wreg[2], wreg[3]);
  __syncthreads();  // drains vmcnt: this block's mask stores complete

  if (tid == 0) {
    __builtin_amdgcn_fence(__ATOMIC_RELEASE, "agent");
    sh_old = __hip_atomic_fetch_add(&cnt[b], 1u, __ATOMIC_ACQ_REL,
                                    __HIP_MEMORY_SCOPE_AGENT);
  }
  __syncthreads();
  if (sh_old != 7) return;  // not the last block of this image
  __builtin_amdgcn_fence(__ATOMIC_ACQUIRE, "agent");

  // ---- last block: word-serial greedy scan + masked output
  int lane = tid & 63, wv = tid >> 6;
  const float4* rowv = (const float4*)(pred + ((size_t)b * NN + n) * NF);
  float4 r0 = rowv[0], r1 = rowv[1], r2 = rowv[2], r3 = rowv[3];
  float obj = r1.x, cls = r3.w;
  float score = __fmul_rn(cls, obj);
  bool valid = (obj > CONF) && (score > CONF);
  uint64_t bal = __ballot(valid);
  if (lane == 0) {
    vbits[2 * wv] = (uint32_t)bal;
    vbits[2 * wv + 1] = (uint32_t)(bal >> 32);
  }
  __syncthreads();

  if (tid < 32) {
    int l = tid;
    uint32_t kw = vbits[l];
    const uint4* mc = (const uint4*)(mask + (size_t)b * (32 * TOPK) + (size_t)l * TOPK);
    uint32_t cur[32], nxt[32];
    #pragma unroll
    for (int q = 0; q < 8; ++q) *(uint4*)&cur[4 * q] = mc[q];
    for (int w = 0; w < 32; ++w) {
      if (w < 31) {
        #pragma unroll
        for (int q = 0; q < 8; ++q) *(uint4*)&nxt[4 * q] = mc[(w + 1) * 8 + q];
      }
      uint32_t rw = kw;
      #pragma unroll
      for (int t = 0; t < 32; ++t)
        if ((rw >> t) & 1u) rw &= ~cur[t];
      uint32_t rf = __shfl(rw, w, 64);
      if (l == w) {
        kw = rf;
      } else if (l > w) {
        uint32_t acc = 0;
        #pragma unroll
        for (int t = 0; t < 32; ++t) acc |= ((rf >> t) & 1u) ? cur[t] : 0u;
        kw &= ~acc;
      }
      if (w < 31) {
        #pragma unroll
        for (int t = 0; t < 32; ++t) cur[t] = nxt[t];
      }
    }
    keepw[l] = kw;
  }
  __syncthreads();

  bool kept = (keepw[tid >> 5] >> (tid & 31)) & 1u;
  float m = kept ? 1.0f : 0.0f;
  float hw = __fmul_rn(r0.z, 0.5f), hh = __fmul_rn(r0.w, 0.5f);
  float4 o0 = make_float4(__fsub_rn(r0.x, hw) * m, __fsub_rn(r0.y, hh) * m,
                          __fadd_rn(r0.x, hw) * m, __fadd_rn(r0.y, hh) * m);
  float4 o1 = make_float4(score * m, r1.y * m, r1.z * m, r1.w * m);
  float4 o2 = make_float4(r2.x * m, r2.y * m, r2.z * m, r2.w * m);
  float4 o3 = make_float4(r3.x * m, r3.y * m, r3.z * m, 0.0f);
  float4* dst = (float4*)(det + ((size_t)b * TOPK + tid) * NF);
  dst[0] = o0; dst[1] = o1; dst[2] = o2; dst[3] = o3;
  keep_out[(size_t)b * TOPK + tid] = m;
}

extern "C" void kernel_launch(void* const* d_in, const int* in_sizes, int n_in,
                              void* d_out, int out_size, void* d_ws, size_t ws_size,
                              hipStream_t stream) {
  const float* pred = (const float*)d_in[0];
  float* det = (float*)d_out;
  float* keep = det + (size_t)NB * TOPK * NF;

  uint8_t* ws = (uint8_t*)d_ws;
  uint32_t* keys = (uint32_t*)ws;                                   // NB*NN u32
  int* sel = (int*)(ws + (size_t)NB * NN * 4);                      // NB*TOPK i32
  uint32_t* mask = (uint32_t*)(ws + (size_t)NB * NN * 4
                                  + (size_t)NB * TOPK * 4);         // NB*32*TOPK u32
  uint32_t* cnt = (uint32_t*)(ws + (size_t)NB * NN * 4
                                 + (size_t)NB * TOPK * 4
                                 + (size_t)NB * 32 * TOPK * 4);     // NB u32

  k_keys<<<(NB * NN + 255) / 256, 256, 0, stream>>>(pred, keys);
  k_select<<<NB, 1024, 0, stream>>>(keys, sel, cnt);
  dim3 gm(NB, 8);
  k_mask_scan<<<gm, 1024, 0, stream>>>(pred, sel, mask, cnt, det, keep);
}

// Round 12
// 167.017 us; speedup vs baseline: 1.0158x; 1.0158x over previous
//
#include <hip/hip_runtime.h>
#include <stdint.h>

#define NB 32
#define NN 25200
#define NN4 6300          // NN/4, exact
#define TOPK 1024
#define NF 16
#define CONF 0.25f
#define IOU_T 0.45f
#define NBIN 4096
#define CAP 2048
#define KEY_BASE 0xBE800001u  // lowest possible valid key (score just above 0.25)

// monotone-ascending uint32 map of the reference's s = valid ? obj*cls : -1.0
__device__ __forceinline__ uint32_t score_key(float obj, float cls) {
  float score = __fmul_rn(cls, obj);
  bool valid = (obj > CONF) && (score > CONF);
  float s = valid ? score : -1.0f;
  uint32_t u = __float_as_uint(s);
  return (u & 0x80000000u) ? ~u : (u | 0x80000000u);
}

__device__ __forceinline__ uint64_t shfl_xor_u64(uint64_t v, int m) {
  uint32_t lo = __shfl_xor((uint32_t)v, m, 64);
  uint32_t hi = __shfl_xor((uint32_t)(v >> 32), m, 64);
  return ((uint64_t)hi << 32) | lo;
}

// Full-grid key compute: the 51.6 MB strided pred read spread over all 256 CUs
// (R8 lesson: folding this into the 32-block select kernel is a 5x loss).
__global__ void k_keys(const float* __restrict__ pred, uint32_t* __restrict__ keys) {
  int g = blockIdx.x * blockDim.x + threadIdx.x;
  if (g >= NB * NN) return;
  const float* row = pred + (size_t)g * NF;
  keys[g] = score_key(row[4], row[15]);
}

// One block per image. Keys read ONCE into registers (<=7 uint4/thread);
// uniform 4096-bin histogram over the valid-key range -> suffix-scan for the
// rank-1024 crossing bin -> compact bins >= b* (~1026 els, CAP=2048
// zero-padded) -> register bitonic 2048 descending on (key32<<32 | ~n).
// Exact jax.lax.top_k order.
__global__ __launch_bounds__(1024) void k_select(const uint32_t* __restrict__ keys,
                                                 int* __restrict__ sel) {
  int b = blockIdx.x;
  int tid = threadIdx.x;
  int lane = tid & 63, wid = tid >> 6;
  const uint4* kb4 = (const uint4*)(keys + (size_t)b * NN);
  __shared__ uint32_t hist[NBIN];
  __shared__ uint64_t ent[CAP];
  __shared__ uint32_t wsum[16];
  __shared__ uint32_t sh_bin;
  __shared__ uint32_t sh_cnt;
  #pragma unroll
  for (int k = 0; k < 4; ++k) hist[tid + 1024 * k] = 0;
  ent[tid] = 0; ent[tid + 1024] = 0;
  if (tid == 0) { sh_cnt = 0; sh_bin = 0; }
  __syncthreads();

  // phase 1: load keys into registers (single global pass) + histogram
  uint4 kreg[7];
  #pragma unroll
  for (int k = 0; k < 7; ++k) {
    int i = tid + k * 1024;
    if (i < NN4) {
      kreg[k] = kb4[i];
      uint32_t kv[4] = {kreg[k].x, kreg[k].y, kreg[k].z, kreg[k].w};
      #pragma unroll
      for (int c = 0; c < 4; ++c) {
        uint32_t key = kv[c];
        if (key >= KEY_BASE) {
          uint32_t bin = (key - KEY_BASE) >> 12;
          if (bin > NBIN - 1) bin = NBIN - 1;
          atomicAdd(&hist[bin], 1u);
        }
      }
    }
  }
  __syncthreads();

  // phase 2: descending-bin cumulative via shfl scan; find crossing bin
  uint32_t h[4]; uint32_t s = 0;
  #pragma unroll
  for (int k = 0; k < 4; ++k) { h[k] = hist[NBIN - 1 - (4 * tid + k)]; s += h[k]; }
  uint32_t my = s;
  #pragma unroll
  for (int d = 1; d < 64; d <<= 1) {
    uint32_t v = __shfl_up(s, d, 64);
    if (lane >= d) s += v;
  }
  if (lane == 63) wsum[wid] = s;
  __syncthreads();
  uint32_t base = 0;
  for (int w = 0; w < wid; ++w) base += wsum[w];
  uint32_t cum = base + s - my;  // exclusive prefix (descending bins)
  #pragma unroll
  for (int k = 0; k < 4; ++k) {
    if (cum < TOPK && cum + h[k] >= TOPK) sh_bin = (uint32_t)(NBIN - 1 - (4 * tid + k));
    cum += h[k];
  }
  __syncthreads();
  uint32_t thr = KEY_BASE + (sh_bin << 12);

  // phase 3: compact from registers (no second global pass)
  #pragma unroll
  for (int k = 0; k < 7; ++k) {
    int i = tid + k * 1024;
    if (i < NN4) {
      uint32_t kv[4] = {kreg[k].x, kreg[k].y, kreg[k].z, kreg[k].w};
      #pragma unroll
      for (int c = 0; c < 4; ++c) {
        uint32_t key = kv[c];
        if (key >= thr) {
          uint32_t p = atomicAdd(&sh_cnt, 1u);
          if (p < CAP) ent[p] = ((uint64_t)key << 32) | (uint32_t)(~(uint32_t)(4 * i + c));
        }
      }
    }
  }
  __syncthreads();

  // phase 4: register bitonic, 2048 descending, 2 elems/thread
  uint64_t v0 = ent[tid], v1 = ent[tid + 1024];
  for (unsigned kk = 2; kk <= CAP; kk <<= 1) {
    for (unsigned j = kk >> 1; j > 0; j >>= 1) {
      if (j == 1024) {
        uint64_t mx = v0 > v1 ? v0 : v1;
        uint64_t mn = v0 > v1 ? v1 : v0;
        v0 = mx; v1 = mn;  // desc=true for kk=2048
      } else if (j >= 64) {
        __syncthreads();
        ent[tid] = v0; ent[tid + 1024] = v1;
        __syncthreads();
        uint64_t p0 = ent[tid ^ j], p1 = ent[(tid ^ j) + 1024];
        bool low = ((tid & j) == 0);
        bool d0 = ((tid & kk) == 0);
        bool d1 = (((tid + 1024) & kk) == 0);
        v0 = (low != d0) ? (v0 < p0 ? v0 : p0) : (v0 > p0 ? v0 : p0);
        v1 = (low != d1) ? (v1 < p1 ? v1 : p1) : (v1 > p1 ? v1 : p1);
      } else {
        uint64_t p0 = shfl_xor_u64(v0, (int)j);
        uint64_t p1 = shfl_xor_u64(v1, (int)j);
        bool low = ((tid & j) == 0);
        bool d0 = ((tid & kk) == 0);
        bool d1 = (((tid + 1024) & kk) == 0);
        v0 = (low != d0) ? (v0 < p0 ? v0 : p0) : (v0 > p0 ? v0 : p0);
        v1 = (low != d1) ? (v1 < p1 ? v1 : p1) : (v1 > p1 ? v1 : p1);
      }
    }
  }
  uint32_t n = ~(uint32_t)(v0 & 0xFFFFFFFFu);
  if (n >= NN) n = 0;  // safety only
  sel[(size_t)b * TOPK + tid] = (int)n;
}

// grid (NB, 8): block covers rows sblk*128..+127 of one image's 1024x1024
// upper-triangular IoU>thres bitmask. Thread = 4-row x 32-col tile: rg=tid&31
// gives rows i0=sblk*128+rg*4..+3 (boxes in registers), cc=tid>>5 the column
// word. Per j: 5 LDS broadcasts amortized over 4 IoUs. The 4 row-words store
// as one uint4 in column-major mask[b][word][row].
__global__ __launch_bounds__(1024) void k_mask(const float* __restrict__ pred,
                                               const int* __restrict__ sel,
                                               uint32_t* __restrict__ mask) {
  int b = blockIdx.x;
  int sblk = blockIdx.y;
  int tid = threadIdx.x;
  int rg = tid & 31;
  int cc = tid >> 5;
  __shared__ float bx1[TOPK], by1[TOPK], bx2[TOPK], by2[TOPK], bar[TOPK];
  {
    int n = sel[(size_t)b * TOPK + tid];
    const float4* row = (const float4*)(pred + ((size_t)b * NN + n) * NF);
    float4 r0 = row[0];
    float hw = __fmul_rn(r0.z, 0.5f), hh = __fmul_rn(r0.w, 0.5f);
    float x1 = __fsub_rn(r0.x, hw), y1 = __fsub_rn(r0.y, hh);
    float x2 = __fadd_rn(r0.x, hw), y2 = __fadd_rn(r0.y, hh);
    bx1[tid] = x1; by1[tid] = y1; bx2[tid] = x2; by2[tid] = y2;
    bar[tid] = __fmul_rn(__fsub_rn(x2, x1), __fsub_rn(y2, y1));
  }
  __syncthreads();
  int i0 = sblk * 128 + rg * 4;   // rows i0..i0+3, all in word iw
  int iw = i0 >> 5;
  uint32_t wreg[4] = {0u, 0u, 0u, 0u};
  if (cc >= iw) {
    float rx1[4], ry1[4], rx2[4], ry2[4], rar[4];
    #pragma unroll
    for (int k = 0; k < 4; ++k) {
      rx1[k] = bx1[i0 + k]; ry1[k] = by1[i0 + k];
      rx2[k] = bx2[i0 + k]; ry2[k] = by2[i0 + k]; rar[k] = bar[i0 + k];
    }
    for (int jj = 0; jj < 32; ++jj) {
      int j = cc * 32 + jj;
      float cx1 = bx1[j], cy1 = by1[j], cx2 = bx2[j], cy2 = by2[j], car = bar[j];
      #pragma unroll
      for (int k = 0; k < 4; ++k) {
        float lx = fmaxf(rx1[k], cx1);
        float ly = fmaxf(ry1[k], cy1);
        float rx = fminf(rx2[k], cx2);
        float ry = fminf(ry2[k], cy2);
        float wd = fmaxf(__fsub_rn(rx, lx), 0.0f);
        float ht = fmaxf(__fsub_rn(ry, ly), 0.0f);
        float inter = __fmul_rn(wd, ht);
        float den = __fadd_rn(__fsub_rn(__fadd_rn(rar[k], car), inter), 1e-7f);
        float iou = __fdiv_rn(inter, den);
        wreg[k] |= (iou > IOU_T ? 1u : 0u) << jj;
      }
    }
    if (cc == iw) {
      #pragma unroll
      for (int k = 0; k < 4; ++k)
        wreg[k] &= ~((2u << ((i0 + k) & 31)) - 1u);  // keep only j > i
    }
  }
  uint4 out = make_uint4(wreg[0], wreg[1], wreg[2], wreg[3]);
  *(uint4*)&mask[((size_t)b * 32 + cc) * TOPK + i0] = out;
}

// One block per image. Word-serial greedy scan: 32 outer iterations; lane l
// owns keep word l; register double-buffered mask loads overlap compute.
// First 8 mask loads hoisted above the pred gather to hide their latency.
// launch_bounds(1024,4): 128-VGPR cap so cur[32]+nxt[32] stay in registers.
__global__ __launch_bounds__(1024, 4) void k_scan_out(const float* __restrict__ pred,
                                                      const int* __restrict__ sel,
                                                      const uint32_t* __restrict__ mask,
                                                      float* __restrict__ det,
                                                      float* __restrict__ keep_out) {
  int b = blockIdx.x;
  int tid = threadIdx.x;
  int lane = tid & 63, wv = tid >> 6;
  __shared__ uint32_t vbits[32];
  __shared__ uint32_t keepw[32];

  // early prefetch of the serial chain's first mask block (wave 0 only)
  uint32_t cur[32];
  const uint4* mc = nullptr;
  if (tid < 32) {
    mc = (const uint4*)(mask + (size_t)b * (32 * TOPK) + (size_t)tid * TOPK);
    #pragma unroll
    for (int q = 0; q < 8; ++q) *(uint4*)&cur[4 * q] = mc[q];
  }

  int n = sel[(size_t)b * TOPK + tid];
  const float4* rowv = (const float4*)(pred + ((size_t)b * NN + n) * NF);
  float4 r0 = rowv[0], r1 = rowv[1], r2 = rowv[2], r3 = rowv[3];
  float obj = r1.x, cls = r3.w;
  float score = __fmul_rn(cls, obj);
  bool valid = (obj > CONF) && (score > CONF);
  uint64_t bal = __ballot(valid);
  if (lane == 0) {
    vbits[2 * wv] = (uint32_t)bal;
    vbits[2 * wv + 1] = (uint32_t)(bal >> 32);
  }
  __syncthreads();

  if (tid < 32) {
    int l = tid;
    uint32_t kw = vbits[l];
    uint32_t nxt[32];
    for (int w = 0; w < 32; ++w) {
      if (w < 31) {
        #pragma unroll
        for (int q = 0; q < 8; ++q) *(uint4*)&nxt[4 * q] = mc[(w + 1) * 8 + q];
      }
      uint32_t rw = kw;
      #pragma unroll
      for (int t = 0; t < 32; ++t)
        if ((rw >> t) & 1u) rw &= ~cur[t];
      uint32_t rf = __shfl(rw, w, 64);
      if (l == w) {
        kw = rf;
      } else if (l > w) {
        uint32_t acc = 0;
        #pragma unroll
        for (int t = 0; t < 32; ++t) acc |= ((rf >> t) & 1u) ? cur[t] : 0u;
        kw &= ~acc;
      }
      if (w < 31) {
        #pragma unroll
        for (int t = 0; t < 32; ++t) cur[t] = nxt[t];
      }
    }
    keepw[l] = kw;
  }
  __syncthreads();

  bool kept = (keepw[tid >> 5] >> (tid & 31)) & 1u;
  float m = kept ? 1.0f : 0.0f;
  float hw = __fmul_rn(r0.z, 0.5f), hh = __fmul_rn(r0.w, 0.5f);
  float4 o0 = make_float4(__fsub_rn(r0.x, hw) * m, __fsub_rn(r0.y, hh) * m,
                          __fadd_rn(r0.x, hw) * m, __fadd_rn(r0.y, hh) * m);
  float4 o1 = make_float4(score * m, r1.y * m, r1.z * m, r1.w * m);
  float4 o2 = make_float4(r2.x * m, r2.y * m, r2.z * m, r2.w * m);
  float4 o3 = make_float4(r3.x * m, r3.y * m, r3.z * m, 0.0f);
  float4* dst = (float4*)(det + ((size_t)b * TOPK + tid) * NF);
  dst[0] = o0; dst[1] = o1; dst[2] = o2; dst[3] = o3;
  keep_out[(size_t)b * TOPK + tid] = m;
}

extern "C" void kernel_launch(void* const* d_in, const int* in_sizes, int n_in,
                              void* d_out, int out_size, void* d_ws, size_t ws_size,
                              hipStream_t stream) {
  const float* pred = (const float*)d_in[0];
  float* det = (float*)d_out;
  float* keep = det + (size_t)NB * TOPK * NF;

  uint8_t* ws = (uint8_t*)d_ws;
  uint32_t* keys = (uint32_t*)ws;                                   // NB*NN u32
  int* sel = (int*)(ws + (size_t)NB * NN * 4);                      // NB*TOPK i32
  uint32_t* mask = (uint32_t*)(ws + (size_t)NB * NN * 4
                                  + (size_t)NB * TOPK * 4);         // NB*32*TOPK u32

  k_keys<<<(NB * NN + 255) / 256, 256, 0, stream>>>(pred, keys);
  k_select<<<NB, 1024, 0, stream>>>(keys, sel);
  dim3 gm(NB, 8);
  k_mask<<<gm, 1024, 0, stream>>>(pred, sel, mask);
  k_scan_out<<<NB, 1024, 0, stream>>>(pred, sel, mask, det, keep);
}